// Round 2
// baseline (793.004 us; speedup 1.0000x reference)
//
#include <hip/hip_runtime.h>
#include <hip/hip_bf16.h>

typedef __bf16 bf16_t;
typedef __bf16 bf16x8 __attribute__((ext_vector_type(8)));
typedef float f32x4 __attribute__((ext_vector_type(4)));

#define B_    2
#define T_    2048
#define DIM_  2048
#define H_    16
#define HKV_  4
#define D_    128
#define KVDIM_ 512

// ---- dtype helpers --------------------------------------------------------
__device__ __forceinline__ bf16x8 load8(const bf16_t* p) {
  return *(const bf16x8*)p;
}
__device__ __forceinline__ bf16x8 load8(const float* p) {
  f32x4 a = *(const f32x4*)p;
  f32x4 b = *(const f32x4*)(p + 4);
  bf16x8 r;
  r[0] = (bf16_t)a[0]; r[1] = (bf16_t)a[1]; r[2] = (bf16_t)a[2]; r[3] = (bf16_t)a[3];
  r[4] = (bf16_t)b[0]; r[5] = (bf16_t)b[1]; r[6] = (bf16_t)b[2]; r[7] = (bf16_t)b[3];
  return r;
}
__device__ __forceinline__ void store1(float* p, float v)  { *p = v; }
__device__ __forceinline__ void store1(bf16_t* p, float v) { *p = (bf16_t)v; }

// ---------------------------------------------------------------------------
// GEMM: C[M,N] = A[M,K] @ W[N,K]^T   (bf16 MFMA, fp32 accum)
// 64x64 tile, 4 waves in 2x2 of 32x32, K-step 32.
// ---------------------------------------------------------------------------
#define GLD 40  // LDS row stride (bf16): 32 + 8 pad

template <typename TA, typename TC>
__global__ __launch_bounds__(256)
void gemm_bt(const TA* __restrict__ A, const float* __restrict__ W,
             TC* __restrict__ C, int M, int N, int K) {
  __shared__ bf16_t As[64 * GLD];
  __shared__ bf16_t Ws[64 * GLD];
  const int tid  = threadIdx.x;
  const int wave = tid >> 6, lane = tid & 63;
  const int l16  = lane & 15, lg = lane >> 4;
  const int m0 = blockIdx.y * 64, n0 = blockIdx.x * 64;
  const int wm = (wave & 1) * 32, wn = (wave >> 1) * 32;
  const int srow = tid >> 2, scol = (tid & 3) * 8;
  const TA*    Ap = A + (size_t)(m0 + srow) * K + scol;
  const float* Wp = W + (size_t)(n0 + srow) * K + scol;
  f32x4 acc[2][2] = {};
  for (int k0 = 0; k0 < K; k0 += 32) {
    bf16x8 av = load8(Ap + k0);
    bf16x8 wv = load8(Wp + k0);
    __syncthreads();
    *(bf16x8*)&As[srow * GLD + scol] = av;
    *(bf16x8*)&Ws[srow * GLD + scol] = wv;
    __syncthreads();
    bf16x8 af0 = *(const bf16x8*)&As[(wm + l16) * GLD + lg * 8];
    bf16x8 af1 = *(const bf16x8*)&As[(wm + 16 + l16) * GLD + lg * 8];
    bf16x8 bf0 = *(const bf16x8*)&Ws[(wn + l16) * GLD + lg * 8];
    bf16x8 bf1 = *(const bf16x8*)&Ws[(wn + 16 + l16) * GLD + lg * 8];
    acc[0][0] = __builtin_amdgcn_mfma_f32_16x16x32_bf16(af0, bf0, acc[0][0], 0, 0, 0);
    acc[0][1] = __builtin_amdgcn_mfma_f32_16x16x32_bf16(af0, bf1, acc[0][1], 0, 0, 0);
    acc[1][0] = __builtin_amdgcn_mfma_f32_16x16x32_bf16(af1, bf0, acc[1][0], 0, 0, 0);
    acc[1][1] = __builtin_amdgcn_mfma_f32_16x16x32_bf16(af1, bf1, acc[1][1], 0, 0, 0);
  }
#pragma unroll
  for (int i = 0; i < 2; i++)
#pragma unroll
    for (int j = 0; j < 2; j++) {
      int row = m0 + wm + i * 16 + lg * 4;
      int col = n0 + wn + j * 16 + l16;
#pragma unroll
      for (int r = 0; r < 4; r++)
        store1(&C[(size_t)(row + r) * N + col], acc[i][j][r]);
    }
}

// ---------------------------------------------------------------------------
// Per-head RMSNorm (fp32 eps, no weight) + NTK RoPE (+ optional per-head gain)
// One wave per 128-elem head row; in-place on bf16.
// ---------------------------------------------------------------------------
__global__ __launch_bounds__(256)
void qk_norm_rope(bf16_t* __restrict__ X, int nheads, int applyGain,
                  const float* __restrict__ gain) {
  const int lane = threadIdx.x & 63;
  const int row  = blockIdx.x * 4 + (threadIdx.x >> 6);
  const int h = row % nheads;
  const int t = (row / nheads) % T_;
  bf16_t* p = X + (size_t)row * D_;
  float x0 = (float)p[lane * 2 + 0];
  float x1 = (float)p[lane * 2 + 1];
  float ss = x0 * x0 + x1 * x1;
#pragma unroll
  for (int m = 32; m >= 1; m >>= 1) ss += __shfl_xor(ss, m);
  const float rn = rsqrtf(ss * (1.0f / 128.0f) + 1.1920929e-07f);
  x0 *= rn; x1 *= rn;
  const float y0 = __shfl_xor(x0, 32);
  const float y1 = __shfl_xor(x1, 32);
  const int i0 = (lane & 31) * 2;
  // base = 10000 * 2^(128/126); kfreq = -log2(base)/64
  const float kfreq = -0.22349352180347601f;
  float s0, c0, s1, c1;
  float a0 = (float)t * exp2f(kfreq * (float)i0);
  float a1 = (float)t * exp2f(kfreq * (float)(i0 + 1));
  sincosf(a0, &s0, &c0);
  sincosf(a1, &s1, &c1);
  float o0, o1;
  if (lane < 32) {  // first half: x1*cos + x2*sin
    o0 = x0 * c0 + y0 * s0;
    o1 = x1 * c1 + y1 * s1;
  } else {          // second half: -x1*sin + x2*cos
    o0 = x0 * c0 - y0 * s0;
    o1 = x1 * c1 - y1 * s1;
  }
  if (applyGain) {
    float g = gain[h];
    o0 *= g; o1 *= g;
  }
  p[lane * 2 + 0] = (bf16_t)o0;
  p[lane * 2 + 1] = (bf16_t)o1;
}

// ---------------------------------------------------------------------------
// Causal GQA flash attention. Block = 64 q rows (4 waves x 16), K-blocks of 32.
// Q [B,T,H,128] bf16, K [B,T,HKV,128] bf16, V [B,T,HKV,128] fp32,
// Y [B,T,H,128] bf16.
// ---------------------------------------------------------------------------
#define KLD 136  // K tile row stride (bf16): 128+8
#define VLD 40   // V^T tile row stride (bf16): 32+8
#define PLD 36   // P scratch row stride (fp32): 32+4

__global__ __launch_bounds__(256)
void flash_attn(const bf16_t* __restrict__ Q, const bf16_t* __restrict__ Kg,
                const float* __restrict__ V, bf16_t* __restrict__ Y) {
  __shared__ bf16_t Ks[32 * KLD];
  __shared__ bf16_t Vs[D_ * VLD];     // transposed [dim][key]
  __shared__ float  Ps[4][16 * PLD];  // per-wave P scratch
  const int tid  = threadIdx.x;
  const int wave = tid >> 6, lane = tid & 63;
  const int l16  = lane & 15, lg = lane >> 4;
  const int b = blockIdx.z, h = blockIdx.y;
  const int q0 = blockIdx.x * 64;
  const int hk = h >> 2;            // G = 4
  const int qrow = q0 + wave * 16;  // this wave's 16 q rows

  const bf16_t* qbase = Q + (((size_t)b * T_ + (qrow + l16)) * H_ + h) * D_;
  bf16x8 qf[4];
#pragma unroll
  for (int kk = 0; kk < 4; kk++)
    qf[kk] = *(const bf16x8*)(qbase + kk * 32 + lg * 8);

  f32x4 o[8] = {};
  float mrow[4] = {-1e30f, -1e30f, -1e30f, -1e30f};
  float lrow[4] = {0.f, 0.f, 0.f, 0.f};
  const float scale = 0.08838834764831845f;  // 1/sqrt(128)
  const float l2e = 1.44269504088896f;

  const int nkb = (q0 + 64) / 32;
  for (int kb = 0; kb < nkb; kb++) {
    const int k0 = kb * 32;
    __syncthreads();
    // stage K tile [32][128] row-major (bf16 source)
    for (int c = tid; c < 512; c += 256) {
      int sr = c >> 4, sc = (c & 15) * 8;
      bf16x8 kv = *(const bf16x8*)(Kg + (((size_t)b * T_ + (k0 + sr)) * HKV_ + hk) * D_ + sc);
      *(bf16x8*)&Ks[sr * KLD + sc] = kv;
    }
    // stage V transposed: Vs[dim][key]  (fp32 source -> bf16)
    {
      int sp = (tid & 15) * 2, d0 = (tid >> 4) * 8;
      const float* vb = V + (((size_t)b * T_ + (k0 + sp)) * HKV_ + hk) * D_ + d0;
      bf16x8 va  = load8(vb);
      bf16x8 vbn = load8(vb + HKV_ * D_);
      const unsigned short* au = (const unsigned short*)&va;
      const unsigned short* bu = (const unsigned short*)&vbn;
#pragma unroll
      for (int i = 0; i < 8; i++) {
        unsigned int pr = (unsigned int)au[i] | ((unsigned int)bu[i] << 16);
        *(unsigned int*)&Vs[(d0 + i) * VLD + sp] = pr;
      }
    }
    __syncthreads();
    if (k0 > qrow + 15) continue;  // fully masked for this wave (wave-uniform)

    // S = Q K^T  (16 q x 32 keys), C-layout
    f32x4 s0 = {}, s1 = {};
#pragma unroll
    for (int kk = 0; kk < 4; kk++) {
      bf16x8 kf0 = *(const bf16x8*)&Ks[l16 * KLD + kk * 32 + lg * 8];
      bf16x8 kf1 = *(const bf16x8*)&Ks[(16 + l16) * KLD + kk * 32 + lg * 8];
      s0 = __builtin_amdgcn_mfma_f32_16x16x32_bf16(qf[kk], kf0, s0, 0, 0, 0);
      s1 = __builtin_amdgcn_mfma_f32_16x16x32_bf16(qf[kk], kf1, s1, 0, 0, 0);
    }
    // scale + causal mask + online softmax (row r lives in lane group lg)
    const int myq = qrow + lg * 4;
    float alpha[4];
#pragma unroll
    for (int r = 0; r < 4; r++) {
      float v0 = s0[r] * scale;
      float v1 = s1[r] * scale;
      if (k0 + l16 > myq + r)      v0 = -1e30f;
      if (k0 + 16 + l16 > myq + r) v1 = -1e30f;
      float mx = fmaxf(v0, v1);
      mx = fmaxf(mx, __shfl_xor(mx, 1));
      mx = fmaxf(mx, __shfl_xor(mx, 2));
      mx = fmaxf(mx, __shfl_xor(mx, 4));
      mx = fmaxf(mx, __shfl_xor(mx, 8));
      float mnew = fmaxf(mrow[r], mx);
      float a  = exp2f((mrow[r] - mnew) * l2e);
      float p0 = exp2f((v0 - mnew) * l2e);
      float p1 = exp2f((v1 - mnew) * l2e);
      float ps = p0 + p1;
      ps += __shfl_xor(ps, 1);
      ps += __shfl_xor(ps, 2);
      ps += __shfl_xor(ps, 4);
      ps += __shfl_xor(ps, 8);
      mrow[r] = mnew;
      lrow[r] = lrow[r] * a + ps;
      alpha[r] = a;
      s0[r] = p0; s1[r] = p1;
    }
#pragma unroll
    for (int f = 0; f < 8; f++)
#pragma unroll
      for (int r = 0; r < 4; r++) o[f][r] *= alpha[r];
    // P: C-layout -> A-layout bf16 via per-wave LDS round trip
    float* pw = Ps[wave];
#pragma unroll
    for (int r = 0; r < 4; r++) {
      pw[(lg * 4 + r) * PLD + l16]      = s0[r];
      pw[(lg * 4 + r) * PLD + 16 + l16] = s1[r];
    }
    __threadfence_block();  // wave-local LDS ordering (waves diverge; no barrier)
    f32x4 pa0 = *(const f32x4*)&pw[l16 * PLD + lg * 8];
    f32x4 pa1 = *(const f32x4*)&pw[l16 * PLD + lg * 8 + 4];
    bf16x8 pf;
    pf[0] = (bf16_t)pa0[0]; pf[1] = (bf16_t)pa0[1];
    pf[2] = (bf16_t)pa0[2]; pf[3] = (bf16_t)pa0[3];
    pf[4] = (bf16_t)pa1[0]; pf[5] = (bf16_t)pa1[1];
    pf[6] = (bf16_t)pa1[2]; pf[7] = (bf16_t)pa1[3];
    // O += P V  (B-frag contiguous from transposed Vs)
#pragma unroll
    for (int f = 0; f < 8; f++) {
      bf16x8 vf = *(const bf16x8*)&Vs[(f * 16 + l16) * VLD + lg * 8];
      o[f] = __builtin_amdgcn_mfma_f32_16x16x32_bf16(pf, vf, o[f], 0, 0, 0);
    }
  }
  // epilogue: divide by l, store bf16
  float rl[4];
#pragma unroll
  for (int r = 0; r < 4; r++) rl[r] = 1.0f / lrow[r];
#pragma unroll
  for (int f = 0; f < 8; f++)
#pragma unroll
    for (int r = 0; r < 4; r++) {
      int t = qrow + lg * 4 + r;
      Y[(((size_t)b * T_ + t) * H_ + h) * D_ + f * 16 + l16] = (bf16_t)(o[f][r] * rl[r]);
    }
}

// ---------------------------------------------------------------------------
extern "C" void kernel_launch(void* const* d_in, const int* in_sizes, int n_in,
                              void* d_out, int out_size, void* d_ws, size_t ws_size,
                              hipStream_t stream) {
  (void)in_sizes; (void)n_in; (void)out_size; (void)ws_size;
  const float* x     = (const float*)d_in[0];
  const float* Wq    = (const float*)d_in[1];
  const float* Wk    = (const float*)d_in[2];
  const float* Wv    = (const float*)d_in[3];
  const float* Wproj = (const float*)d_in[4];
  const float* qgain = (const float*)d_in[5];

  float* out  = (float*)d_out;                   // [B,T,DIM] fp32
  float* vout = out + (size_t)B_ * T_ * DIM_;    // [B,T,HKV,D] fp32 (2nd output)

  bf16_t* Qp = (bf16_t*)d_ws;                    // [B,T,H,D]   bf16, 16 MB
  bf16_t* Kp = Qp + (size_t)B_ * T_ * DIM_;      // [B,T,HKV,D] bf16,  4 MB
  bf16_t* Yp = Kp + (size_t)B_ * T_ * KVDIM_;    // [B,T,H,D]   bf16, 16 MB

  const int M = B_ * T_;  // 4096
  dim3 blk(256);

  // projections (V written straight into its fp32 output slot)
  gemm_bt<float, bf16_t><<<dim3(DIM_ / 64,   M / 64), blk, 0, stream>>>(x, Wq, Qp,   M, DIM_,   DIM_);
  gemm_bt<float, bf16_t><<<dim3(KVDIM_ / 64, M / 64), blk, 0, stream>>>(x, Wk, Kp,   M, KVDIM_, DIM_);
  gemm_bt<float, float> <<<dim3(KVDIM_ / 64, M / 64), blk, 0, stream>>>(x, Wv, vout, M, KVDIM_, DIM_);
  // QK norm + rope (+ q gain)
  qk_norm_rope<<<dim3(M * H_ / 4),   blk, 0, stream>>>(Qp, H_,   1, qgain);
  qk_norm_rope<<<dim3(M * HKV_ / 4), blk, 0, stream>>>(Kp, HKV_, 0, qgain);
  // attention
  flash_attn<<<dim3(T_ / 64, H_, B_), blk, 0, stream>>>(Qp, Kp, vout, Yp);
  // output projection (bf16 A, fp32 W, fp32 C)
  gemm_bt<bf16_t, float><<<dim3(DIM_ / 64, M / 64), blk, 0, stream>>>(Yp, Wproj, out, M, DIM_, DIM_);
}

// Round 3
// 434.745 us; speedup vs baseline: 1.8241x; 1.8241x over previous
//
#include <hip/hip_runtime.h>
#include <hip/hip_bf16.h>

typedef __bf16 bf16_t;
typedef __bf16 bf16x4 __attribute__((ext_vector_type(4)));
typedef __bf16 bf16x8 __attribute__((ext_vector_type(8)));
typedef float f32x4 __attribute__((ext_vector_type(4)));

#define B_    2
#define T_    2048
#define DIM_  2048
#define H_    16
#define HKV_  4
#define D_    128
#define KVDIM_ 512

// ---- helpers --------------------------------------------------------------
__device__ __forceinline__ bf16x8 cvt8(f32x4 a, f32x4 b) {
  bf16x8 r;
  r[0] = (bf16_t)a[0]; r[1] = (bf16_t)a[1]; r[2] = (bf16_t)a[2]; r[3] = (bf16_t)a[3];
  r[4] = (bf16_t)b[0]; r[5] = (bf16_t)b[1]; r[6] = (bf16_t)b[2]; r[7] = (bf16_t)b[3];
  return r;
}
__device__ __forceinline__ bf16x4 cvt4(f32x4 a) {
  bf16x4 r;
  r[0] = (bf16_t)a[0]; r[1] = (bf16_t)a[1]; r[2] = (bf16_t)a[2]; r[3] = (bf16_t)a[3];
  return r;
}
// async global->LDS, 16B per lane; LDS dest = wave-uniform base + lane*16
__device__ __forceinline__ void g2l16(const void* g, void* l) {
  __builtin_amdgcn_global_load_lds(
      (const __attribute__((address_space(1))) unsigned int*)g,
      (__attribute__((address_space(3))) unsigned int*)l, 16, 0, 0);
}

// ---------------------------------------------------------------------------
// fp32 -> bf16 bulk convert (grid sized exactly: n = grid*256*8)
// ---------------------------------------------------------------------------
__global__ __launch_bounds__(256)
void cvt_bf16(const float* __restrict__ s, bf16_t* __restrict__ d) {
  size_t i = ((size_t)blockIdx.x * 256 + threadIdx.x) * 8;
  f32x4 a = *(const f32x4*)(s + i);
  f32x4 b = *(const f32x4*)(s + i + 4);
  *(bf16x8*)(d + i) = cvt8(a, b);
}

// ---------------------------------------------------------------------------
// GEMM: C[M,N] = A[M,K] @ W[N,K]^T  (bf16 MFMA, fp32 accum), 128x128 tile,
// BK=32, 4 waves each computing a 64x64 sub-tile (4x4 of 16x16 MFMAs).
// AASYNC/WASYNC: operand is bf16 in global -> global_load_lds (unpadded LDS);
// else fp32 in global -> VGPR convert staging (padded LDS).
// MODE 0: C bf16.  MODE 2: C fp32.  MODE 1 (KV): cols<512 -> Kp bf16;
// cols>=512 -> Vb bf16 + Vf fp32.  (Wg2 = Wv for the non-async KV path.)
// ---------------------------------------------------------------------------
template <int MODE, bool AASYNC, bool WASYNC>
__global__ __launch_bounds__(256)
void gemm128(const void* __restrict__ Ag, const void* __restrict__ Wg,
             const void* __restrict__ Wg2, void* __restrict__ Cb,
             bf16_t* __restrict__ Vb, float* __restrict__ Vf,
             int M, int N, int K) {
  constexpr int LDA = AASYNC ? 32 : 40;
  constexpr int LDW = WASYNC ? 32 : 40;
  __shared__ bf16_t As[128 * LDA];
  __shared__ bf16_t Ws[128 * LDW];
  const int tid  = threadIdx.x;
  const int wave = tid >> 6, lane = tid & 63;
  const int l16  = lane & 15, lg = lane >> 4;
  const int m0 = blockIdx.y * 128, n0 = blockIdx.x * 128;
  const int wm = (wave & 1) * 64, wn = (wave >> 1) * 64;
  f32x4 acc[4][4] = {};

  for (int k0 = 0; k0 < K; k0 += 32) {
    __syncthreads();
    // ---- stage A ----
    if constexpr (AASYNC) {
      const bf16_t* A = (const bf16_t*)Ag;
      const int r = lane >> 2, c8 = (lane & 3) * 8;
      g2l16(&A[(size_t)(m0 + wave * 32 + r) * K + k0 + c8],      &As[(wave * 32) * LDA]);
      g2l16(&A[(size_t)(m0 + wave * 32 + 16 + r) * K + k0 + c8], &As[(wave * 32 + 16) * LDA]);
    } else {
      const float* A = (const float*)Ag;
#pragma unroll
      for (int j = 0; j < 4; j++) {
        int row = wave * 32 + j * 8 + (lane >> 3);
        int cf  = (lane & 7) * 4;
        f32x4 v = *(const f32x4*)&A[(size_t)(m0 + row) * K + k0 + cf];
        *(bf16x4*)&As[row * LDA + cf] = cvt4(v);
      }
    }
    // ---- stage W ----
    if constexpr (WASYNC) {
      const bf16_t* W = (const bf16_t*)Wg;
      const int r = lane >> 2, c8 = (lane & 3) * 8;
      g2l16(&W[(size_t)(n0 + wave * 32 + r) * K + k0 + c8],      &Ws[(wave * 32) * LDW]);
      g2l16(&W[(size_t)(n0 + wave * 32 + 16 + r) * K + k0 + c8], &Ws[(wave * 32 + 16) * LDW]);
    } else {
      const float* W;
      int nb;
      if constexpr (MODE == 1) {
        if (n0 < 512) { W = (const float*)Wg;  nb = n0; }
        else          { W = (const float*)Wg2; nb = n0 - 512; }
      } else { W = (const float*)Wg; nb = n0; }
#pragma unroll
      for (int j = 0; j < 4; j++) {
        int row = wave * 32 + j * 8 + (lane >> 3);
        int cf  = (lane & 7) * 4;
        f32x4 v = *(const f32x4*)&W[(size_t)(nb + row) * K + k0 + cf];
        *(bf16x4*)&Ws[row * LDW + cf] = cvt4(v);
      }
    }
    __syncthreads();
    // ---- fragments + 16 MFMA ----
    bf16x8 af[4], bfr[4];
#pragma unroll
    for (int i = 0; i < 4; i++)
      af[i] = *(const bf16x8*)&As[(wm + i * 16 + l16) * LDA + lg * 8];
#pragma unroll
    for (int j = 0; j < 4; j++)
      bfr[j] = *(const bf16x8*)&Ws[(wn + j * 16 + l16) * LDW + lg * 8];
#pragma unroll
    for (int i = 0; i < 4; i++)
#pragma unroll
      for (int j = 0; j < 4; j++)
        acc[i][j] = __builtin_amdgcn_mfma_f32_16x16x32_bf16(af[i], bfr[j], acc[i][j], 0, 0, 0);
  }
  // ---- epilogue ----
#pragma unroll
  for (int i = 0; i < 4; i++)
#pragma unroll
    for (int j = 0; j < 4; j++) {
      int row = m0 + wm + i * 16 + lg * 4;
      int col = n0 + wn + j * 16 + l16;
#pragma unroll
      for (int r = 0; r < 4; r++) {
        float v = acc[i][j][r];
        if constexpr (MODE == 0) {
          ((bf16_t*)Cb)[(size_t)(row + r) * N + col] = (bf16_t)v;
        } else if constexpr (MODE == 2) {
          ((float*)Cb)[(size_t)(row + r) * N + col] = v;
        } else {
          if (col < 512) ((bf16_t*)Cb)[(size_t)(row + r) * 512 + col] = (bf16_t)v;
          else {
            int c = col - 512;
            Vb[(size_t)(row + r) * 512 + c] = (bf16_t)v;
            Vf[(size_t)(row + r) * 512 + c] = v;
          }
        }
      }
    }
}

// ---------------------------------------------------------------------------
// Per-head RMSNorm (fp32 eps, no weight) + NTK RoPE (+ optional per-head gain)
// One wave per 128-elem head row; in-place on bf16.  (validated round 2)
// ---------------------------------------------------------------------------
__global__ __launch_bounds__(256)
void qk_norm_rope(bf16_t* __restrict__ X, int nheads, int applyGain,
                  const float* __restrict__ gain) {
  const int lane = threadIdx.x & 63;
  const int row  = blockIdx.x * 4 + (threadIdx.x >> 6);
  const int h = row % nheads;
  const int t = (row / nheads) % T_;
  bf16_t* p = X + (size_t)row * D_;
  float x0 = (float)p[lane * 2 + 0];
  float x1 = (float)p[lane * 2 + 1];
  float ss = x0 * x0 + x1 * x1;
#pragma unroll
  for (int m = 32; m >= 1; m >>= 1) ss += __shfl_xor(ss, m);
  const float rn = rsqrtf(ss * (1.0f / 128.0f) + 1.1920929e-07f);
  x0 *= rn; x1 *= rn;
  const float y0 = __shfl_xor(x0, 32);
  const float y1 = __shfl_xor(x1, 32);
  const int i0 = (lane & 31) * 2;
  const float kfreq = -0.22349352180347601f;  // -log2(1e4*2^(128/126))/64
  float s0, c0, s1, c1;
  float a0 = (float)t * exp2f(kfreq * (float)i0);
  float a1 = (float)t * exp2f(kfreq * (float)(i0 + 1));
  sincosf(a0, &s0, &c0);
  sincosf(a1, &s1, &c1);
  float o0, o1;
  if (lane < 32) { o0 = x0 * c0 + y0 * s0;  o1 = x1 * c1 + y1 * s1; }
  else           { o0 = x0 * c0 - y0 * s0;  o1 = x1 * c1 - y1 * s1; }
  if (applyGain) { float g = gain[h]; o0 *= g; o1 *= g; }
  p[lane * 2 + 0] = (bf16_t)o0;
  p[lane * 2 + 1] = (bf16_t)o1;
}

// ---------------------------------------------------------------------------
// Causal GQA flash attention v2.
// Block = 128 q rows, 4 waves; wave w owns m-tiles {q0+16w, q0+64+16w} (16 rows
// each, interleaved for diagonal balance).  KB = 64 keys/iteration.
// Static-max softmax: scores bounded by sqrt(128)*gain ~ 11.32 (RMS-normed q,k),
// so p = exp2(s*C) directly -- no max tracking, no rescale, no in-loop shuffles.
// Q,K,V bf16; Y bf16 (may alias Q: each block reads its own q rows first).
// ---------------------------------------------------------------------------
#define KLD 136  // K tile row stride (bf16): 128+8 -> 272B rows (16B aligned)
#define VLD 72   // V^T tile row stride (bf16): 64+8 -> 144B rows
#define PLD 68   // P scratch row stride (fp32): 64+4 -> 272B rows

__global__ __launch_bounds__(256, 2)
void flash_attn(const bf16_t* __restrict__ Q, const bf16_t* __restrict__ Kg,
                const bf16_t* __restrict__ V, bf16_t* __restrict__ Y) {
  __shared__ bf16_t Ks[64 * KLD];      // 17408 B  [key][dim]
  __shared__ bf16_t Vs[D_ * VLD];      // 18432 B  [dim][key] (transposed)
  __shared__ float  Ps[4][16 * PLD];   // 17408 B  per-wave P scratch
  const int tid  = threadIdx.x;
  const int wave = tid >> 6, lane = tid & 63;
  const int l16  = lane & 15, lg = lane >> 4;
  const int b = blockIdx.z, h = blockIdx.y;
  const int q0 = blockIdx.x * 128;
  const int hk = h >> 2;  // G = 4

  int qr[2];
  qr[0] = q0 + wave * 16;        // early tile
  qr[1] = q0 + 64 + wave * 16;   // late tile (active every iteration)

  bf16x8 qf[2][4];
#pragma unroll
  for (int mt = 0; mt < 2; mt++)
#pragma unroll
    for (int kk = 0; kk < 4; kk++)
      qf[mt][kk] = *(const bf16x8*)&Q[(((size_t)b * T_ + qr[mt] + l16) * H_ + h) * D_ + kk * 32 + lg * 8];

  f32x4 o[2][8] = {};
  float lsum[2][4] = {};
  const float C = 0.12752531f;  // (1/sqrt(128)) * log2(e)

  const int nkb = (q0 + 128) / 64;
  for (int kb = 0; kb < nkb; kb++) {
    const int k0 = kb * 64;
    __syncthreads();
    // ---- stage K [64][128] row-major ----
    for (int c = tid; c < 1024; c += 256) {
      int sr = c >> 4, sc = (c & 15) * 8;
      *(bf16x8*)&Ks[sr * KLD + sc] =
          *(const bf16x8*)&Kg[(((size_t)b * T_ + k0 + sr) * HKV_ + hk) * D_ + sc];
    }
    // ---- stage V transposed [dim][key] ----
#pragma unroll
    for (int it = 0; it < 2; it++) {
      int sp = (tid & 31) * 2, d0 = ((tid >> 5) + it * 8) * 8;
      const bf16_t* vb = &V[(((size_t)b * T_ + k0 + sp) * HKV_ + hk) * D_ + d0];
      bf16x8 va = *(const bf16x8*)vb;
      bf16x8 vc = *(const bf16x8*)(vb + HKV_ * D_);
      const unsigned short* au = (const unsigned short*)&va;
      const unsigned short* bu = (const unsigned short*)&vc;
#pragma unroll
      for (int i = 0; i < 8; i++) {
        unsigned int pr = (unsigned int)au[i] | ((unsigned int)bu[i] << 16);
        *(unsigned int*)&Vs[(d0 + i) * VLD + sp] = pr;
      }
    }
    __syncthreads();

    const bool act0 = (k0 <= qr[0] + 15);  // early tile still has unmasked keys

    // ---- S = Q K^T ----
    f32x4 s[2][4] = {};
#pragma unroll
    for (int kk = 0; kk < 4; kk++) {
      bf16x8 kf[4];
#pragma unroll
      for (int f = 0; f < 4; f++)
        kf[f] = *(const bf16x8*)&Ks[(f * 16 + l16) * KLD + kk * 32 + lg * 8];
      if (act0)
#pragma unroll
        for (int f = 0; f < 4; f++)
          s[0][f] = __builtin_amdgcn_mfma_f32_16x16x32_bf16(qf[0][kk], kf[f], s[0][f], 0, 0, 0);
#pragma unroll
      for (int f = 0; f < 4; f++)
        s[1][f] = __builtin_amdgcn_mfma_f32_16x16x32_bf16(qf[1][kk], kf[f], s[1][f], 0, 0, 0);
    }
    // ---- softmax (no max subtraction; scores structurally bounded) ----
    bf16x8 pf[2][2];
    float* pw = Ps[wave];
#pragma unroll
    for (int mt = 0; mt < 2; mt++) {
      if (mt == 0 && !act0) continue;
      const int myq = qr[mt] + lg * 4;
#pragma unroll
      for (int f = 0; f < 4; f++)
#pragma unroll
        for (int r = 0; r < 4; r++) {
          int kcol = k0 + f * 16 + l16;
          float p = (kcol <= myq + r) ? exp2f(s[mt][f][r] * C) : 0.0f;
          lsum[mt][r] += p;
          pw[(lg * 4 + r) * PLD + f * 16 + l16] = p;
        }
      __threadfence_block();  // wave-local LDS write->read ordering
      f32x4 pa0 = *(const f32x4*)&pw[l16 * PLD + lg * 8];
      f32x4 pa1 = *(const f32x4*)&pw[l16 * PLD + lg * 8 + 4];
      f32x4 pb0 = *(const f32x4*)&pw[l16 * PLD + 32 + lg * 8];
      f32x4 pb1 = *(const f32x4*)&pw[l16 * PLD + 32 + lg * 8 + 4];
      pf[mt][0] = cvt8(pa0, pa1);
      pf[mt][1] = cvt8(pb0, pb1);
      __threadfence_block();  // reads drain before next mt overwrites
    }
    // ---- O += P V ----
#pragma unroll
    for (int f = 0; f < 8; f++) {
      bf16x8 v0 = *(const bf16x8*)&Vs[(f * 16 + l16) * VLD + lg * 8];
      bf16x8 v1 = *(const bf16x8*)&Vs[(f * 16 + l16) * VLD + 32 + lg * 8];
      if (act0) {
        o[0][f] = __builtin_amdgcn_mfma_f32_16x16x32_bf16(pf[0][0], v0, o[0][f], 0, 0, 0);
        o[0][f] = __builtin_amdgcn_mfma_f32_16x16x32_bf16(pf[0][1], v1, o[0][f], 0, 0, 0);
      }
      o[1][f] = __builtin_amdgcn_mfma_f32_16x16x32_bf16(pf[1][0], v0, o[1][f], 0, 0, 0);
      o[1][f] = __builtin_amdgcn_mfma_f32_16x16x32_bf16(pf[1][1], v1, o[1][f], 0, 0, 0);
    }
  }
  // ---- epilogue: reduce l across the 16-lane row group, normalize, store ----
#pragma unroll
  for (int mt = 0; mt < 2; mt++) {
    float rl[4];
#pragma unroll
    for (int r = 0; r < 4; r++) {
      float l = lsum[mt][r];
      l += __shfl_xor(l, 1);
      l += __shfl_xor(l, 2);
      l += __shfl_xor(l, 4);
      l += __shfl_xor(l, 8);
      rl[r] = 1.0f / l;
    }
#pragma unroll
    for (int f = 0; f < 8; f++)
#pragma unroll
      for (int r = 0; r < 4; r++) {
        int t = qr[mt] + lg * 4 + r;
        Y[(((size_t)b * T_ + t) * H_ + h) * D_ + f * 16 + l16] = (bf16_t)(o[mt][f][r] * rl[r]);
      }
  }
}

// ---------------------------------------------------------------------------
extern "C" void kernel_launch(void* const* d_in, const int* in_sizes, int n_in,
                              void* d_out, int out_size, void* d_ws, size_t ws_size,
                              hipStream_t stream) {
  (void)in_sizes; (void)n_in; (void)out_size;
  const float* x     = (const float*)d_in[0];
  const float* Wq    = (const float*)d_in[1];
  const float* Wk    = (const float*)d_in[2];
  const float* Wv    = (const float*)d_in[3];
  const float* Wproj = (const float*)d_in[4];
  const float* qgain = (const float*)d_in[5];

  float* out  = (float*)d_out;                  // [B,T,DIM] fp32
  float* vout = out + (size_t)B_ * T_ * DIM_;   // [B,T,HKV,D] fp32

  const size_t M = (size_t)B_ * T_;  // 4096
  char* ws = (char*)d_ws;
  size_t off = 0;
  auto take = [&](size_t elems) { bf16_t* p = (bf16_t*)(ws + off); off += elems * sizeof(bf16_t); return p; };

  bf16_t* Qp = take(M * DIM_);     // Q (then aliased as Y)  16 MB
  bf16_t* Kp = take(M * KVDIM_);   //  4 MB
  bf16_t* Vb = take(M * KVDIM_);   //  4 MB

  const size_t cvt_elems = M * DIM_ + (size_t)DIM_ * DIM_ + (size_t)(2 * KVDIM_) * DIM_ + (size_t)DIM_ * DIM_;
  const bool fast = (ws_size >= off + cvt_elems * sizeof(bf16_t));

  dim3 blk(256);
  if (fast) {
    bf16_t* xb   = take(M * DIM_);                    // 16 MB
    bf16_t* Wqb  = take((size_t)DIM_ * DIM_);         //  8 MB
    bf16_t* Wkvb = take((size_t)2 * KVDIM_ * DIM_);   //  4 MB (Wk rows 0..511, Wv rows 512..1023)
    bf16_t* Wpb  = take((size_t)DIM_ * DIM_);         //  8 MB

    cvt_bf16<<<dim3((unsigned)(M * DIM_ / 2048)), blk, 0, stream>>>(x, xb);
    cvt_bf16<<<dim3((unsigned)((size_t)DIM_ * DIM_ / 2048)), blk, 0, stream>>>(Wq, Wqb);
    cvt_bf16<<<dim3((unsigned)((size_t)KVDIM_ * DIM_ / 2048)), blk, 0, stream>>>(Wk, Wkvb);
    cvt_bf16<<<dim3((unsigned)((size_t)KVDIM_ * DIM_ / 2048)), blk, 0, stream>>>(Wv, Wkvb + (size_t)KVDIM_ * DIM_);
    cvt_bf16<<<dim3((unsigned)((size_t)DIM_ * DIM_ / 2048)), blk, 0, stream>>>(Wproj, Wpb);

    gemm128<0, true, true><<<dim3(DIM_ / 128, M / 128), blk, 0, stream>>>(
        xb, Wqb, nullptr, Qp, nullptr, nullptr, M, DIM_, DIM_);
    gemm128<1, true, true><<<dim3(2 * KVDIM_ / 128, M / 128), blk, 0, stream>>>(
        xb, Wkvb, nullptr, Kp, Vb, vout, M, 2 * KVDIM_, DIM_);
  } else {
    gemm128<0, false, false><<<dim3(DIM_ / 128, M / 128), blk, 0, stream>>>(
        x, Wq, nullptr, Qp, nullptr, nullptr, M, DIM_, DIM_);
    gemm128<1, false, false><<<dim3(2 * KVDIM_ / 128, M / 128), blk, 0, stream>>>(
        x, Wk, Wv, Kp, Vb, vout, M, 2 * KVDIM_, DIM_);
  }

  qk_norm_rope<<<dim3((unsigned)(M * H_ / 4)), blk, 0, stream>>>(Qp, H_, 1, qgain);
  qk_norm_rope<<<dim3((unsigned)(M * HKV_ / 4)), blk, 0, stream>>>(Kp, HKV_, 0, qgain);

  // Y aliases Qp: each block reads only its own q rows (into regs) before storing
  flash_attn<<<dim3(T_ / 128, H_, B_), blk, 0, stream>>>(Qp, Kp, Vb, Qp);

  if (fast) {
    bf16_t* Wpb = (bf16_t*)(ws + (3 * M * KVDIM_ + 2 * M * DIM_ + (size_t)DIM_ * DIM_) * 0 /*unused*/);
    // recompute Wpb pointer deterministically (same layout as above)
    size_t o2 = (M * DIM_ + M * KVDIM_ + M * KVDIM_ + M * DIM_ + (size_t)DIM_ * DIM_ + (size_t)2 * KVDIM_ * DIM_) * sizeof(bf16_t);
    Wpb = (bf16_t*)(ws + o2);
    gemm128<2, true, true><<<dim3(DIM_ / 128, M / 128), blk, 0, stream>>>(
        Qp, Wpb, nullptr, out, nullptr, nullptr, M, DIM_, DIM_);
  } else {
    gemm128<2, true, false><<<dim3(DIM_ / 128, M / 128), blk, 0, stream>>>(
        Qp, Wproj, nullptr, out, nullptr, nullptr, M, DIM_, DIM_);
  }
}

// Round 4
// 398.990 us; speedup vs baseline: 1.9875x; 1.0896x over previous
//
#include <hip/hip_runtime.h>
#include <hip/hip_bf16.h>

typedef __bf16 bf16_t;
typedef __bf16 bf16x4 __attribute__((ext_vector_type(4)));
typedef __bf16 bf16x8 __attribute__((ext_vector_type(8)));
typedef float f32x4 __attribute__((ext_vector_type(4)));

#define B_    2
#define T_    2048
#define DIM_  2048
#define H_    16
#define HKV_  4
#define D_    128
#define KVDIM_ 512

// ---- helpers --------------------------------------------------------------
__device__ __forceinline__ bf16x8 cvt8(f32x4 a, f32x4 b) {
  bf16x8 r;
  r[0] = (bf16_t)a[0]; r[1] = (bf16_t)a[1]; r[2] = (bf16_t)a[2]; r[3] = (bf16_t)a[3];
  r[4] = (bf16_t)b[0]; r[5] = (bf16_t)b[1]; r[6] = (bf16_t)b[2]; r[7] = (bf16_t)b[3];
  return r;
}
__device__ __forceinline__ bf16x4 cvt4(f32x4 a) {
  bf16x4 r;
  r[0] = (bf16_t)a[0]; r[1] = (bf16_t)a[1]; r[2] = (bf16_t)a[2]; r[3] = (bf16_t)a[3];
  return r;
}
// async global->LDS, 16B per lane; LDS dest = wave-uniform base + lane*16
__device__ __forceinline__ void g2l16(const void* g, void* l) {
  __builtin_amdgcn_global_load_lds(
      (const __attribute__((address_space(1))) unsigned int*)g,
      (__attribute__((address_space(3))) unsigned int*)l, 16, 0, 0);
}

// ---------------------------------------------------------------------------
// Fused fp32 -> bf16 convert for all 5 tensors (one launch).
// Segments in 2048-elem blocks: x:4096 | Wq:2048 | Wk:512 | Wv:512 | Wp:2048
// ---------------------------------------------------------------------------
__global__ __launch_bounds__(256)
void cvt_all(const float* __restrict__ x,  const float* __restrict__ wq,
             const float* __restrict__ wk, const float* __restrict__ wv,
             const float* __restrict__ wp, bf16_t* __restrict__ xb,
             bf16_t* __restrict__ wqb, bf16_t* __restrict__ wkvb,
             bf16_t* __restrict__ wpb) {
  int blk = blockIdx.x;
  const float* s; bf16_t* d; int lb;
  if (blk < 4096)      { s = x;  d = xb;                          lb = blk; }
  else if (blk < 6144) { s = wq; d = wqb;                         lb = blk - 4096; }
  else if (blk < 6656) { s = wk; d = wkvb;                        lb = blk - 6144; }
  else if (blk < 7168) { s = wv; d = wkvb + (size_t)KVDIM_ * DIM_; lb = blk - 6656; }
  else                 { s = wp; d = wpb;                         lb = blk - 7168; }
  size_t i = (size_t)lb * 2048 + (size_t)threadIdx.x * 8;
  f32x4 a = *(const f32x4*)(s + i);
  f32x4 b = *(const f32x4*)(s + i + 4);
  *(bf16x8*)(d + i) = cvt8(a, b);
}

// ---------------------------------------------------------------------------
// GEMM: C[M,N] = A[M,K] @ W[N,K]^T  (bf16 MFMA, fp32 accum), 128x128 tile,
// BK=32, 4 waves each computing a 64x64 sub-tile.  (validated round 3)
// ---------------------------------------------------------------------------
template <int MODE, bool AASYNC, bool WASYNC>
__global__ __launch_bounds__(256)
void gemm128(const void* __restrict__ Ag, const void* __restrict__ Wg,
             const void* __restrict__ Wg2, void* __restrict__ Cb,
             bf16_t* __restrict__ Vb, float* __restrict__ Vf,
             int M, int N, int K) {
  constexpr int LDA = AASYNC ? 32 : 40;
  constexpr int LDW = WASYNC ? 32 : 40;
  __shared__ bf16_t As[128 * LDA];
  __shared__ bf16_t Ws[128 * LDW];
  const int tid  = threadIdx.x;
  const int wave = tid >> 6, lane = tid & 63;
  const int l16  = lane & 15, lg = lane >> 4;
  const int m0 = blockIdx.y * 128, n0 = blockIdx.x * 128;
  const int wm = (wave & 1) * 64, wn = (wave >> 1) * 64;
  f32x4 acc[4][4] = {};

  for (int k0 = 0; k0 < K; k0 += 32) {
    __syncthreads();
    if constexpr (AASYNC) {
      const bf16_t* A = (const bf16_t*)Ag;
      const int r = lane >> 2, c8 = (lane & 3) * 8;
      g2l16(&A[(size_t)(m0 + wave * 32 + r) * K + k0 + c8],      &As[(wave * 32) * LDA]);
      g2l16(&A[(size_t)(m0 + wave * 32 + 16 + r) * K + k0 + c8], &As[(wave * 32 + 16) * LDA]);
    } else {
      const float* A = (const float*)Ag;
#pragma unroll
      for (int j = 0; j < 4; j++) {
        int row = wave * 32 + j * 8 + (lane >> 3);
        int cf  = (lane & 7) * 4;
        f32x4 v = *(const f32x4*)&A[(size_t)(m0 + row) * K + k0 + cf];
        *(bf16x4*)&As[row * LDA + cf] = cvt4(v);
      }
    }
    if constexpr (WASYNC) {
      const bf16_t* W = (const bf16_t*)Wg;
      const int r = lane >> 2, c8 = (lane & 3) * 8;
      g2l16(&W[(size_t)(n0 + wave * 32 + r) * K + k0 + c8],      &Ws[(wave * 32) * LDW]);
      g2l16(&W[(size_t)(n0 + wave * 32 + 16 + r) * K + k0 + c8], &Ws[(wave * 32 + 16) * LDW]);
    } else {
      const float* W;
      int nb;
      if constexpr (MODE == 1) {
        if (n0 < 512) { W = (const float*)Wg;  nb = n0; }
        else          { W = (const float*)Wg2; nb = n0 - 512; }
      } else { W = (const float*)Wg; nb = n0; }
#pragma unroll
      for (int j = 0; j < 4; j++) {
        int row = wave * 32 + j * 8 + (lane >> 3);
        int cf  = (lane & 7) * 4;
        f32x4 v = *(const f32x4*)&W[(size_t)(nb + row) * K + k0 + cf];
        *(bf16x4*)&Ws[row * LDW + cf] = cvt4(v);
      }
    }
    __syncthreads();
    bf16x8 af[4], bfr[4];
#pragma unroll
    for (int i = 0; i < 4; i++)
      af[i] = *(const bf16x8*)&As[(wm + i * 16 + l16) * LDA + lg * 8];
#pragma unroll
    for (int j = 0; j < 4; j++)
      bfr[j] = *(const bf16x8*)&Ws[(wn + j * 16 + l16) * LDW + lg * 8];
#pragma unroll
    for (int i = 0; i < 4; i++)
#pragma unroll
      for (int j = 0; j < 4; j++)
        acc[i][j] = __builtin_amdgcn_mfma_f32_16x16x32_bf16(af[i], bfr[j], acc[i][j], 0, 0, 0);
  }
#pragma unroll
  for (int i = 0; i < 4; i++)
#pragma unroll
    for (int j = 0; j < 4; j++) {
      int row = m0 + wm + i * 16 + lg * 4;
      int col = n0 + wn + j * 16 + l16;
#pragma unroll
      for (int r = 0; r < 4; r++) {
        float v = acc[i][j][r];
        if constexpr (MODE == 0) {
          ((bf16_t*)Cb)[(size_t)(row + r) * N + col] = (bf16_t)v;
        } else if constexpr (MODE == 2) {
          ((float*)Cb)[(size_t)(row + r) * N + col] = v;
        } else {
          if (col < 512) ((bf16_t*)Cb)[(size_t)(row + r) * 512 + col] = (bf16_t)v;
          else {
            int c = col - 512;
            Vb[(size_t)(row + r) * 512 + c] = (bf16_t)v;
            Vf[(size_t)(row + r) * 512 + c] = v;
          }
        }
      }
    }
}

// ---------------------------------------------------------------------------
// Fused QK RMSNorm + NTK RoPE (+ q gain).  One wave per 128-elem head row.
// Rows [0, M*H) -> Q (gain); rows [M*H, M*H + M*HKV) -> K (no gain).
// ---------------------------------------------------------------------------
__global__ __launch_bounds__(256)
void qk_norm_rope(bf16_t* __restrict__ Qp, bf16_t* __restrict__ Kp,
                  const float* __restrict__ gain) {
  const int lane = threadIdx.x & 63;
  int row = blockIdx.x * 4 + (threadIdx.x >> 6);
  bf16_t* Xp; int nh; bool ag;
  const int MQ = B_ * T_ * H_;
  if (row < MQ) { Xp = Qp; nh = H_;  ag = true; }
  else          { Xp = Kp; nh = HKV_; ag = false; row -= MQ; }
  const int h = row % nh;
  const int t = (row / nh) % T_;
  bf16_t* p = Xp + (size_t)row * D_;
  float x0 = (float)p[lane * 2 + 0];
  float x1 = (float)p[lane * 2 + 1];
  float ss = x0 * x0 + x1 * x1;
#pragma unroll
  for (int m = 32; m >= 1; m >>= 1) ss += __shfl_xor(ss, m);
  const float rn = rsqrtf(ss * (1.0f / 128.0f) + 1.1920929e-07f);
  x0 *= rn; x1 *= rn;
  const float y0 = __shfl_xor(x0, 32);
  const float y1 = __shfl_xor(x1, 32);
  const int i0 = (lane & 31) * 2;
  const float kfreq = -0.22349352180347601f;  // -log2(1e4*2^(128/126))/64
  float s0, c0, s1, c1;
  float a0 = (float)t * exp2f(kfreq * (float)i0);
  float a1 = (float)t * exp2f(kfreq * (float)(i0 + 1));
  sincosf(a0, &s0, &c0);
  sincosf(a1, &s1, &c1);
  float o0, o1;
  if (lane < 32) { o0 = x0 * c0 + y0 * s0;  o1 = x1 * c1 + y1 * s1; }
  else           { o0 = x0 * c0 - y0 * s0;  o1 = x1 * c1 - y1 * s1; }
  if (ag) { float g = gain[h]; o0 *= g; o1 *= g; }
  p[lane * 2 + 0] = (bf16_t)o0;
  p[lane * 2 + 1] = (bf16_t)o1;
}

// ---------------------------------------------------------------------------
// Causal GQA flash attention v3 — balanced tile pairing.
// 32 q-tiles of 64 rows.  Block pi handles tiles {pi, 31-pi}: total compute
// is 33 m-tile iterations for every block (perfect causal balance).
// 4 waves x 16 rows per tile; KB = 64 keys/iter; static-max softmax
// (RMS-normed q,k => |s| <= sqrt(128)*gain); masking only on the diagonal
// iteration of each tile (wave-uniform branch).
// ---------------------------------------------------------------------------
#define KLD 136  // K tile row stride (bf16): 128+8
#define VLD 72   // V^T tile row stride (bf16): 64+8
#define PLD 68   // P scratch row stride (fp32): 64+4

__global__ __launch_bounds__(256, 2)
void flash_attn(const bf16_t* __restrict__ Q, const bf16_t* __restrict__ Kg,
                const bf16_t* __restrict__ V, bf16_t* __restrict__ Y) {
  __shared__ bf16_t Ks[64 * KLD];      // 17408 B  [key][dim]
  __shared__ bf16_t Vs[D_ * VLD];      // 18432 B  [dim][key] transposed
  __shared__ float  Ps[4][16 * PLD];   // 17408 B  per-wave P scratch
  const int tid  = threadIdx.x;
  const int wave = tid >> 6, lane = tid & 63;
  const int l16  = lane & 15, lg = lane >> 4;
  const int b = blockIdx.z, h = blockIdx.y;
  const int pi = blockIdx.x;           // pair index 0..15
  const int hk = h >> 2;               // G = 4

  int qr[2];
  qr[0] = 64 * pi + 16 * wave;         // early tile (active while kb <= pi)
  qr[1] = 64 * (31 - pi) + 16 * wave;  // late tile (active all iterations)

  bf16x8 qf[2][4];
#pragma unroll
  for (int mt = 0; mt < 2; mt++)
#pragma unroll
    for (int kk = 0; kk < 4; kk++)
      qf[mt][kk] = *(const bf16x8*)&Q[(((size_t)b * T_ + qr[mt] + l16) * H_ + h) * D_ + kk * 32 + lg * 8];

  f32x4 o[2][8] = {};
  float lsum[2][4] = {};
  const float C = 0.12752531f;  // (1/sqrt(128)) * log2(e)

  const int nkb = 32 - pi;
  for (int kb = 0; kb < nkb; kb++) {
    const int k0 = kb * 64;
    __syncthreads();
    // ---- stage K [64][128] row-major ----
    for (int c = tid; c < 1024; c += 256) {
      int sr = c >> 4, sc = (c & 15) * 8;
      *(bf16x8*)&Ks[sr * KLD + sc] =
          *(const bf16x8*)&Kg[(((size_t)b * T_ + k0 + sr) * HKV_ + hk) * D_ + sc];
    }
    // ---- stage V transposed [dim][key] ----
#pragma unroll
    for (int it = 0; it < 2; it++) {
      int sp = (tid & 31) * 2, d0 = ((tid >> 5) + it * 8) * 8;
      const bf16_t* vb = &V[(((size_t)b * T_ + k0 + sp) * HKV_ + hk) * D_ + d0];
      bf16x8 va = *(const bf16x8*)vb;
      bf16x8 vc = *(const bf16x8*)(vb + HKV_ * D_);
      const unsigned short* au = (const unsigned short*)&va;
      const unsigned short* bu = (const unsigned short*)&vc;
#pragma unroll
      for (int i = 0; i < 8; i++) {
        unsigned int pr = (unsigned int)au[i] | ((unsigned int)bu[i] << 16);
        *(unsigned int*)&Vs[(d0 + i) * VLD + sp] = pr;
      }
    }
    __syncthreads();

    const bool act0 = (kb <= pi);

    // ---- S = Q K^T ----
    f32x4 s[2][4] = {};
#pragma unroll
    for (int kk = 0; kk < 4; kk++) {
      bf16x8 kf[4];
#pragma unroll
      for (int f = 0; f < 4; f++)
        kf[f] = *(const bf16x8*)&Ks[(f * 16 + l16) * KLD + kk * 32 + lg * 8];
      if (act0)
#pragma unroll
        for (int f = 0; f < 4; f++)
          s[0][f] = __builtin_amdgcn_mfma_f32_16x16x32_bf16(qf[0][kk], kf[f], s[0][f], 0, 0, 0);
#pragma unroll
      for (int f = 0; f < 4; f++)
        s[1][f] = __builtin_amdgcn_mfma_f32_16x16x32_bf16(qf[1][kk], kf[f], s[1][f], 0, 0, 0);
    }
    // ---- softmax: clean path off-diagonal, masked path on diagonal ----
    bf16x8 pf[2][2];
    float* pw = Ps[wave];
#pragma unroll
    for (int mt = 0; mt < 2; mt++) {
      if (mt == 0 && !act0) continue;
      const bool diag = (mt == 0) ? (kb == pi) : (kb == nkb - 1);
      if (diag) {
        const int myq = qr[mt] + lg * 4;
#pragma unroll
        for (int f = 0; f < 4; f++)
#pragma unroll
          for (int r = 0; r < 4; r++) {
            int kcol = k0 + f * 16 + l16;
            float p = (kcol <= myq + r) ? exp2f(s[mt][f][r] * C) : 0.0f;
            lsum[mt][r] += p;
            pw[(lg * 4 + r) * PLD + f * 16 + l16] = p;
          }
      } else {
#pragma unroll
        for (int f = 0; f < 4; f++)
#pragma unroll
          for (int r = 0; r < 4; r++) {
            float p = exp2f(s[mt][f][r] * C);
            lsum[mt][r] += p;
            pw[(lg * 4 + r) * PLD + f * 16 + l16] = p;
          }
      }
      __threadfence_block();  // wave-local LDS write->read ordering
      f32x4 pa0 = *(const f32x4*)&pw[l16 * PLD + lg * 8];
      f32x4 pa1 = *(const f32x4*)&pw[l16 * PLD + lg * 8 + 4];
      f32x4 pb0 = *(const f32x4*)&pw[l16 * PLD + 32 + lg * 8];
      f32x4 pb1 = *(const f32x4*)&pw[l16 * PLD + 32 + lg * 8 + 4];
      pf[mt][0] = cvt8(pa0, pa1);
      pf[mt][1] = cvt8(pb0, pb1);
      __threadfence_block();  // reads drain before next mt overwrites
    }
    // ---- O += P V ----
#pragma unroll
    for (int f = 0; f < 8; f++) {
      bf16x8 v0 = *(const bf16x8*)&Vs[(f * 16 + l16) * VLD + lg * 8];
      bf16x8 v1 = *(const bf16x8*)&Vs[(f * 16 + l16) * VLD + 32 + lg * 8];
      if (act0) {
        o[0][f] = __builtin_amdgcn_mfma_f32_16x16x32_bf16(pf[0][0], v0, o[0][f], 0, 0, 0);
        o[0][f] = __builtin_amdgcn_mfma_f32_16x16x32_bf16(pf[0][1], v1, o[0][f], 0, 0, 0);
      }
      o[1][f] = __builtin_amdgcn_mfma_f32_16x16x32_bf16(pf[1][0], v0, o[1][f], 0, 0, 0);
      o[1][f] = __builtin_amdgcn_mfma_f32_16x16x32_bf16(pf[1][1], v1, o[1][f], 0, 0, 0);
    }
  }
  // ---- epilogue ----
#pragma unroll
  for (int mt = 0; mt < 2; mt++) {
    float rl[4];
#pragma unroll
    for (int r = 0; r < 4; r++) {
      float l = lsum[mt][r];
      l += __shfl_xor(l, 1);
      l += __shfl_xor(l, 2);
      l += __shfl_xor(l, 4);
      l += __shfl_xor(l, 8);
      rl[r] = 1.0f / l;
    }
#pragma unroll
    for (int f = 0; f < 8; f++)
#pragma unroll
      for (int r = 0; r < 4; r++) {
        int t = qr[mt] + lg * 4 + r;
        Y[(((size_t)b * T_ + t) * H_ + h) * D_ + f * 16 + l16] = (bf16_t)(o[mt][f][r] * rl[r]);
      }
  }
}

// ---------------------------------------------------------------------------
extern "C" void kernel_launch(void* const* d_in, const int* in_sizes, int n_in,
                              void* d_out, int out_size, void* d_ws, size_t ws_size,
                              hipStream_t stream) {
  (void)in_sizes; (void)n_in; (void)out_size;
  const float* x     = (const float*)d_in[0];
  const float* Wq    = (const float*)d_in[1];
  const float* Wk    = (const float*)d_in[2];
  const float* Wv    = (const float*)d_in[3];
  const float* Wproj = (const float*)d_in[4];
  const float* qgain = (const float*)d_in[5];

  float* out  = (float*)d_out;                  // [B,T,DIM] fp32
  float* vout = out + (size_t)B_ * T_ * DIM_;   // [B,T,HKV,D] fp32

  const size_t M = (size_t)B_ * T_;  // 4096
  char* ws = (char*)d_ws;
  size_t off = 0;
  auto take = [&](size_t elems) { bf16_t* p = (bf16_t*)(ws + off); off += elems * sizeof(bf16_t); return p; };

  bf16_t* Qp = take(M * DIM_);     // Q, later aliased as attention output Y
  bf16_t* Kp = take(M * KVDIM_);
  bf16_t* Vb = take(M * KVDIM_);

  const size_t cvt_elems = M * DIM_ + (size_t)DIM_ * DIM_ + (size_t)(2 * KVDIM_) * DIM_ + (size_t)DIM_ * DIM_;
  const bool fast = (ws_size >= off + cvt_elems * sizeof(bf16_t));

  dim3 blk(256);
  if (fast) {
    bf16_t* xb   = take(M * DIM_);
    bf16_t* Wqb  = take((size_t)DIM_ * DIM_);
    bf16_t* Wkvb = take((size_t)2 * KVDIM_ * DIM_);  // Wk rows 0..511, Wv rows 512..1023
    bf16_t* Wpb  = take((size_t)DIM_ * DIM_);

    cvt_all<<<dim3(9216), blk, 0, stream>>>(x, Wq, Wk, Wv, Wproj, xb, Wqb, Wkvb, Wpb);

    gemm128<0, true, true><<<dim3(DIM_ / 128, M / 128), blk, 0, stream>>>(
        xb, Wqb, nullptr, Qp, nullptr, nullptr, M, DIM_, DIM_);
    gemm128<1, true, true><<<dim3(2 * KVDIM_ / 128, M / 128), blk, 0, stream>>>(
        xb, Wkvb, nullptr, Kp, Vb, vout, M, 2 * KVDIM_, DIM_);

    qk_norm_rope<<<dim3((unsigned)((M * H_ + M * HKV_) / 4)), blk, 0, stream>>>(Qp, Kp, qgain);
    flash_attn<<<dim3(16, H_, B_), blk, 0, stream>>>(Qp, Kp, Vb, Qp);

    gemm128<2, true, true><<<dim3(DIM_ / 128, M / 128), blk, 0, stream>>>(
        Qp, Wpb, nullptr, out, nullptr, nullptr, M, DIM_, DIM_);
  } else {
    gemm128<0, false, false><<<dim3(DIM_ / 128, M / 128), blk, 0, stream>>>(
        x, Wq, nullptr, Qp, nullptr, nullptr, M, DIM_, DIM_);
    gemm128<1, false, false><<<dim3(2 * KVDIM_ / 128, M / 128), blk, 0, stream>>>(
        x, Wk, Wv, Kp, Vb, vout, M, 2 * KVDIM_, DIM_);
    qk_norm_rope<<<dim3((unsigned)((M * H_ + M * HKV_) / 4)), blk, 0, stream>>>(Qp, Kp, qgain);
    flash_attn<<<dim3(16, H_, B_), blk, 0, stream>>>(Qp, Kp, Vb, Qp);
    gemm128<2, true, false><<<dim3(DIM_ / 128, M / 128), blk, 0, stream>>>(
        Qp, Wproj, nullptr, out, nullptr, nullptr, M, DIM_, DIM_);
  }
}

// Round 5
// 337.087 us; speedup vs baseline: 2.3525x; 1.1836x over previous
//
#include <hip/hip_runtime.h>
#include <hip/hip_bf16.h>

typedef __bf16 bf16_t;
typedef __bf16 bf16x4 __attribute__((ext_vector_type(4)));
typedef __bf16 bf16x8 __attribute__((ext_vector_type(8)));
typedef float f32x4 __attribute__((ext_vector_type(4)));

#define B_    2
#define T_    2048
#define DIM_  2048
#define H_    16
#define HKV_  4
#define D_    128
#define KVDIM_ 512

// ---- helpers --------------------------------------------------------------
__device__ __forceinline__ bf16x8 cvt8(f32x4 a, f32x4 b) {
  bf16x8 r;
  r[0] = (bf16_t)a[0]; r[1] = (bf16_t)a[1]; r[2] = (bf16_t)a[2]; r[3] = (bf16_t)a[3];
  r[4] = (bf16_t)b[0]; r[5] = (bf16_t)b[1]; r[6] = (bf16_t)b[2]; r[7] = (bf16_t)b[3];
  return r;
}
__device__ __forceinline__ bf16x4 cvt4(f32x4 a) {
  bf16x4 r;
  r[0] = (bf16_t)a[0]; r[1] = (bf16_t)a[1]; r[2] = (bf16_t)a[2]; r[3] = (bf16_t)a[3];
  return r;
}
// async global->LDS, 16B per lane; LDS dest = wave-uniform base + lane*16
__device__ __forceinline__ void g2l16(const void* g, void* l) {
  __builtin_amdgcn_global_load_lds(
      (const __attribute__((address_space(1))) unsigned int*)g,
      (__attribute__((address_space(3))) unsigned int*)l, 16, 0, 0);
}

// ---------------------------------------------------------------------------
// Fused fp32 -> bf16 convert (one launch).  2048-elem blocks.
// x:4096 | Wq:2048 | Wk:512 | Wv:512 | Wp:2048  (Wq/Wk/Wv -> contiguous Wqkvb)
// ---------------------------------------------------------------------------
__global__ __launch_bounds__(256)
void cvt_all(const float* __restrict__ x,  const float* __restrict__ wq,
             const float* __restrict__ wk, const float* __restrict__ wv,
             const float* __restrict__ wp, bf16_t* __restrict__ xb,
             bf16_t* __restrict__ wqkvb, bf16_t* __restrict__ wpb) {
  int blk = blockIdx.x;
  const float* s; bf16_t* d; int lb;
  if (blk < 4096)      { s = x;  d = xb;                              lb = blk; }
  else if (blk < 6144) { s = wq; d = wqkvb;                           lb = blk - 4096; }
  else if (blk < 6656) { s = wk; d = wqkvb + (size_t)2048 * DIM_;     lb = blk - 6144; }
  else if (blk < 7168) { s = wv; d = wqkvb + (size_t)2560 * DIM_;     lb = blk - 6656; }
  else                 { s = wp; d = wpb;                             lb = blk - 7168; }
  size_t i = (size_t)lb * 2048 + (size_t)threadIdx.x * 8;
  f32x4 a = *(const f32x4*)(s + i);
  f32x4 b = *(const f32x4*)(s + i + 4);
  *(bf16x8*)(d + i) = cvt8(a, b);
}

// ---------------------------------------------------------------------------
// GEMM: C[M,N] = A[M,K] @ W[N,K]^T  (bf16 MFMA, fp32 accum), 128x128 tile,
// BK=32, 4 waves each computing a 64x64 sub-tile.
// MODE 0: C bf16.  MODE 2: C fp32.
// MODE 1: fused QKV epilogue -- col<2048 -> Cb(Q) bf16; col<2560 -> Kb bf16;
//         else Vb bf16 + Vf fp32.
// MODE 3: fallback KV epilogue (W fp32 via Wg/Wg2): col<512 -> Cb(K); else V.
// ---------------------------------------------------------------------------
template <int MODE, bool AASYNC, bool WASYNC>
__global__ __launch_bounds__(256)
void gemm128(const void* __restrict__ Ag, const void* __restrict__ Wg,
             const void* __restrict__ Wg2, void* __restrict__ Cb,
             bf16_t* __restrict__ Kb, bf16_t* __restrict__ Vb,
             float* __restrict__ Vf, int M, int N, int K) {
  constexpr int LDA = AASYNC ? 32 : 40;
  constexpr int LDW = WASYNC ? 32 : 40;
  __shared__ bf16_t As[128 * LDA];
  __shared__ bf16_t Ws[128 * LDW];
  const int tid  = threadIdx.x;
  const int wave = tid >> 6, lane = tid & 63;
  const int l16  = lane & 15, lg = lane >> 4;
  const int m0 = blockIdx.y * 128, n0 = blockIdx.x * 128;
  const int wm = (wave & 1) * 64, wn = (wave >> 1) * 64;
  f32x4 acc[4][4] = {};

  for (int k0 = 0; k0 < K; k0 += 32) {
    __syncthreads();
    if constexpr (AASYNC) {
      const bf16_t* A = (const bf16_t*)Ag;
      const int r = lane >> 2, c8 = (lane & 3) * 8;
      g2l16(&A[(size_t)(m0 + wave * 32 + r) * K + k0 + c8],      &As[(wave * 32) * LDA]);
      g2l16(&A[(size_t)(m0 + wave * 32 + 16 + r) * K + k0 + c8], &As[(wave * 32 + 16) * LDA]);
    } else {
      const float* A = (const float*)Ag;
#pragma unroll
      for (int j = 0; j < 4; j++) {
        int row = wave * 32 + j * 8 + (lane >> 3);
        int cf  = (lane & 7) * 4;
        f32x4 v = *(const f32x4*)&A[(size_t)(m0 + row) * K + k0 + cf];
        *(bf16x4*)&As[row * LDA + cf] = cvt4(v);
      }
    }
    if constexpr (WASYNC) {
      const bf16_t* W = (const bf16_t*)Wg;
      const int r = lane >> 2, c8 = (lane & 3) * 8;
      g2l16(&W[(size_t)(n0 + wave * 32 + r) * K + k0 + c8],      &Ws[(wave * 32) * LDW]);
      g2l16(&W[(size_t)(n0 + wave * 32 + 16 + r) * K + k0 + c8], &Ws[(wave * 32 + 16) * LDW]);
    } else {
      const float* W;
      int nb;
      if constexpr (MODE == 3) {
        if (n0 < 512) { W = (const float*)Wg;  nb = n0; }
        else          { W = (const float*)Wg2; nb = n0 - 512; }
      } else { W = (const float*)Wg; nb = n0; }
#pragma unroll
      for (int j = 0; j < 4; j++) {
        int row = wave * 32 + j * 8 + (lane >> 3);
        int cf  = (lane & 7) * 4;
        f32x4 v = *(const f32x4*)&W[(size_t)(nb + row) * K + k0 + cf];
        *(bf16x4*)&Ws[row * LDW + cf] = cvt4(v);
      }
    }
    __syncthreads();
    bf16x8 af[4], bfr[4];
#pragma unroll
    for (int i = 0; i < 4; i++)
      af[i] = *(const bf16x8*)&As[(wm + i * 16 + l16) * LDA + lg * 8];
#pragma unroll
    for (int j = 0; j < 4; j++)
      bfr[j] = *(const bf16x8*)&Ws[(wn + j * 16 + l16) * LDW + lg * 8];
#pragma unroll
    for (int i = 0; i < 4; i++)
#pragma unroll
      for (int j = 0; j < 4; j++)
        acc[i][j] = __builtin_amdgcn_mfma_f32_16x16x32_bf16(af[i], bfr[j], acc[i][j], 0, 0, 0);
  }
#pragma unroll
  for (int i = 0; i < 4; i++)
#pragma unroll
    for (int j = 0; j < 4; j++) {
      int row = m0 + wm + i * 16 + lg * 4;
      int col = n0 + wn + j * 16 + l16;
#pragma unroll
      for (int r = 0; r < 4; r++) {
        float v = acc[i][j][r];
        if constexpr (MODE == 0) {
          ((bf16_t*)Cb)[(size_t)(row + r) * N + col] = (bf16_t)v;
        } else if constexpr (MODE == 2) {
          ((float*)Cb)[(size_t)(row + r) * N + col] = v;
        } else if constexpr (MODE == 1) {
          if (col < 2048)      ((bf16_t*)Cb)[(size_t)(row + r) * 2048 + col] = (bf16_t)v;
          else if (col < 2560) Kb[(size_t)(row + r) * 512 + (col - 2048)] = (bf16_t)v;
          else {
            int c = col - 2560;
            Vb[(size_t)(row + r) * 512 + c] = (bf16_t)v;
            Vf[(size_t)(row + r) * 512 + c] = v;
          }
        } else {  // MODE 3
          if (col < 512) ((bf16_t*)Cb)[(size_t)(row + r) * 512 + col] = (bf16_t)v;
          else {
            int c = col - 512;
            Vb[(size_t)(row + r) * 512 + c] = (bf16_t)v;
            Vf[(size_t)(row + r) * 512 + c] = v;
          }
        }
      }
    }
}

// ---------------------------------------------------------------------------
// Fused QK RMSNorm + NTK RoPE (+ q gain).  One wave per 128-elem head row.
// ---------------------------------------------------------------------------
__global__ __launch_bounds__(256)
void qk_norm_rope(bf16_t* __restrict__ Qp, bf16_t* __restrict__ Kp,
                  const float* __restrict__ gain) {
  const int lane = threadIdx.x & 63;
  int row = blockIdx.x * 4 + (threadIdx.x >> 6);
  bf16_t* Xp; int nh; bool ag;
  const int MQ = B_ * T_ * H_;
  if (row < MQ) { Xp = Qp; nh = H_;  ag = true; }
  else          { Xp = Kp; nh = HKV_; ag = false; row -= MQ; }
  const int h = row % nh;
  const int t = (row / nh) % T_;
  bf16_t* p = Xp + (size_t)row * D_;
  float x0 = (float)p[lane * 2 + 0];
  float x1 = (float)p[lane * 2 + 1];
  float ss = x0 * x0 + x1 * x1;
#pragma unroll
  for (int m = 32; m >= 1; m >>= 1) ss += __shfl_xor(ss, m);
  const float rn = rsqrtf(ss * (1.0f / 128.0f) + 1.1920929e-07f);
  x0 *= rn; x1 *= rn;
  const float y0 = __shfl_xor(x0, 32);
  const float y1 = __shfl_xor(x1, 32);
  const int i0 = (lane & 31) * 2;
  const float kfreq = -0.22349352180347601f;  // -log2(1e4*2^(128/126))/64
  float s0, c0, s1, c1;
  float a0 = (float)t * exp2f(kfreq * (float)i0);
  float a1 = (float)t * exp2f(kfreq * (float)(i0 + 1));
  sincosf(a0, &s0, &c0);
  sincosf(a1, &s1, &c1);
  float o0, o1;
  if (lane < 32) { o0 = x0 * c0 + y0 * s0;  o1 = x1 * c1 + y1 * s1; }
  else           { o0 = x0 * c0 - y0 * s0;  o1 = x1 * c1 - y1 * s1; }
  if (ag) { float g = gain[h]; o0 *= g; o1 *= g; }
  p[lane * 2 + 0] = (bf16_t)o0;
  p[lane * 2 + 1] = (bf16_t)o1;
}

// ---------------------------------------------------------------------------
// Causal GQA flash attention v4 — balanced pairing + global prefetch pipeline.
// Block pi handles 64-row q-tiles {pi, 31-pi} (33 iterations for every pi).
// Next K/V tile is loaded into VGPRs during current compute; LDS writes at
// the top of the next iteration absorb the vmcnt wait.
// ---------------------------------------------------------------------------
#define KLD 136  // K tile row stride (bf16): 128+8
#define VLD 72   // V^T tile row stride (bf16): 64+8
#define PLD 68   // P scratch row stride (fp32): 64+4

__global__ __launch_bounds__(256, 2)
void flash_attn(const bf16_t* __restrict__ Q, const bf16_t* __restrict__ Kg,
                const bf16_t* __restrict__ V, bf16_t* __restrict__ Y) {
  __shared__ bf16_t Ks[64 * KLD];
  __shared__ bf16_t Vs[D_ * VLD];      // [dim][key] transposed
  __shared__ float  Ps[4][16 * PLD];   // per-wave P scratch
  const int tid  = threadIdx.x;
  const int wave = tid >> 6, lane = tid & 63;
  const int l16  = lane & 15, lg = lane >> 4;
  const int b = blockIdx.z, h = blockIdx.y;
  const int pi = blockIdx.x;           // pair index 0..15
  const int hk = h >> 2;               // G = 4

  int qr[2];
  qr[0] = 64 * pi + 16 * wave;         // early tile (active while kb <= pi)
  qr[1] = 64 * (31 - pi) + 16 * wave;  // late tile (always active)

  bf16x8 qf[2][4];
#pragma unroll
  for (int mt = 0; mt < 2; mt++)
#pragma unroll
    for (int kk = 0; kk < 4; kk++)
      qf[mt][kk] = *(const bf16x8*)&Q[(((size_t)b * T_ + qr[mt] + l16) * H_ + h) * D_ + kk * 32 + lg * 8];

  f32x4 o[2][8] = {};
  float lsum[2][4] = {};
  const float C = 0.12752531f;  // (1/sqrt(128)) * log2(e)

  // staging coords
  const int sr = tid >> 4, sc = (tid & 15) * 8;  // K: 4 rows (sr+16j), 8-col chunks
  const int sp2 = (tid & 31) * 2;                // V: key pair
  const int dvh = (tid >> 5) * 8;                // V: dim chunk base

  bf16x8 kreg[4];
  bf16x8 vreg[2][2];
  auto pf_load = [&](int k0) {
#pragma unroll
    for (int j = 0; j < 4; j++)
      kreg[j] = *(const bf16x8*)&Kg[(((size_t)b * T_ + k0 + sr + 16 * j) * HKV_ + hk) * D_ + sc];
#pragma unroll
    for (int it = 0; it < 2; it++) {
      const bf16_t* vb = &V[(((size_t)b * T_ + k0 + sp2) * HKV_ + hk) * D_ + dvh + it * 64];
      vreg[it][0] = *(const bf16x8*)vb;
      vreg[it][1] = *(const bf16x8*)(vb + HKV_ * D_);
    }
  };
  auto pf_store = [&]() {
#pragma unroll
    for (int j = 0; j < 4; j++)
      *(bf16x8*)&Ks[(sr + 16 * j) * KLD + sc] = kreg[j];
#pragma unroll
    for (int it = 0; it < 2; it++) {
      int dd = dvh + it * 64;
      const unsigned short* au = (const unsigned short*)&vreg[it][0];
      const unsigned short* bu = (const unsigned short*)&vreg[it][1];
#pragma unroll
      for (int i = 0; i < 8; i++) {
        unsigned int pr = (unsigned int)au[i] | ((unsigned int)bu[i] << 16);
        *(unsigned int*)&Vs[(dd + i) * VLD + sp2] = pr;
      }
    }
  };

  const int nkb = 32 - pi;
  pf_load(0);
  for (int kb = 0; kb < nkb; kb++) {
    const int k0 = kb * 64;
    __syncthreads();   // prev iteration's LDS reads done
    pf_store();
    __syncthreads();   // tile visible to all waves
    if (kb + 1 < nkb) pf_load(k0 + 64);  // overlap with compute below

    const bool act0 = (kb <= pi);

    // ---- S = Q K^T ----
    f32x4 s[2][4] = {};
#pragma unroll
    for (int kk = 0; kk < 4; kk++) {
      bf16x8 kf[4];
#pragma unroll
      for (int f = 0; f < 4; f++)
        kf[f] = *(const bf16x8*)&Ks[(f * 16 + l16) * KLD + kk * 32 + lg * 8];
      if (act0)
#pragma unroll
        for (int f = 0; f < 4; f++)
          s[0][f] = __builtin_amdgcn_mfma_f32_16x16x32_bf16(qf[0][kk], kf[f], s[0][f], 0, 0, 0);
#pragma unroll
      for (int f = 0; f < 4; f++)
        s[1][f] = __builtin_amdgcn_mfma_f32_16x16x32_bf16(qf[1][kk], kf[f], s[1][f], 0, 0, 0);
    }
    // ---- softmax (static max; mask only on diagonal iteration) ----
    bf16x8 pf[2][2];
    float* pw = Ps[wave];
#pragma unroll
    for (int mt = 0; mt < 2; mt++) {
      if (mt == 0 && !act0) continue;
      const bool diag = (mt == 0) ? (kb == pi) : (kb == nkb - 1);
      if (diag) {
        const int myq = qr[mt] + lg * 4;
#pragma unroll
        for (int f = 0; f < 4; f++)
#pragma unroll
          for (int r = 0; r < 4; r++) {
            int kcol = k0 + f * 16 + l16;
            float p = (kcol <= myq + r) ? exp2f(s[mt][f][r] * C) : 0.0f;
            lsum[mt][r] += p;
            pw[(lg * 4 + r) * PLD + f * 16 + l16] = p;
          }
      } else {
#pragma unroll
        for (int f = 0; f < 4; f++)
#pragma unroll
          for (int r = 0; r < 4; r++) {
            float p = exp2f(s[mt][f][r] * C);
            lsum[mt][r] += p;
            pw[(lg * 4 + r) * PLD + f * 16 + l16] = p;
          }
      }
      __threadfence_block();
      f32x4 pa0 = *(const f32x4*)&pw[l16 * PLD + lg * 8];
      f32x4 pa1 = *(const f32x4*)&pw[l16 * PLD + lg * 8 + 4];
      f32x4 pb0 = *(const f32x4*)&pw[l16 * PLD + 32 + lg * 8];
      f32x4 pb1 = *(const f32x4*)&pw[l16 * PLD + 32 + lg * 8 + 4];
      pf[mt][0] = cvt8(pa0, pa1);
      pf[mt][1] = cvt8(pb0, pb1);
      __threadfence_block();
    }
    // ---- O += P V ----
#pragma unroll
    for (int f = 0; f < 8; f++) {
      bf16x8 v0 = *(const bf16x8*)&Vs[(f * 16 + l16) * VLD + lg * 8];
      bf16x8 v1 = *(const bf16x8*)&Vs[(f * 16 + l16) * VLD + 32 + lg * 8];
      if (act0) {
        o[0][f] = __builtin_amdgcn_mfma_f32_16x16x32_bf16(pf[0][0], v0, o[0][f], 0, 0, 0);
        o[0][f] = __builtin_amdgcn_mfma_f32_16x16x32_bf16(pf[0][1], v1, o[0][f], 0, 0, 0);
      }
      o[1][f] = __builtin_amdgcn_mfma_f32_16x16x32_bf16(pf[1][0], v0, o[1][f], 0, 0, 0);
      o[1][f] = __builtin_amdgcn_mfma_f32_16x16x32_bf16(pf[1][1], v1, o[1][f], 0, 0, 0);
    }
  }
  // ---- epilogue ----
#pragma unroll
  for (int mt = 0; mt < 2; mt++) {
    float rl[4];
#pragma unroll
    for (int r = 0; r < 4; r++) {
      float l = lsum[mt][r];
      l += __shfl_xor(l, 1);
      l += __shfl_xor(l, 2);
      l += __shfl_xor(l, 4);
      l += __shfl_xor(l, 8);
      rl[r] = 1.0f / l;
    }
#pragma unroll
    for (int f = 0; f < 8; f++)
#pragma unroll
      for (int r = 0; r < 4; r++) {
        int t = qr[mt] + lg * 4 + r;
        Y[(((size_t)b * T_ + t) * H_ + h) * D_ + f * 16 + l16] = (bf16_t)(o[mt][f][r] * rl[r]);
      }
  }
}

// ---------------------------------------------------------------------------
extern "C" void kernel_launch(void* const* d_in, const int* in_sizes, int n_in,
                              void* d_out, int out_size, void* d_ws, size_t ws_size,
                              hipStream_t stream) {
  (void)in_sizes; (void)n_in; (void)out_size;
  const float* x     = (const float*)d_in[0];
  const float* Wq    = (const float*)d_in[1];
  const float* Wk    = (const float*)d_in[2];
  const float* Wv    = (const float*)d_in[3];
  const float* Wproj = (const float*)d_in[4];
  const float* qgain = (const float*)d_in[5];

  float* out  = (float*)d_out;                  // [B,T,DIM] fp32
  float* vout = out + (size_t)B_ * T_ * DIM_;   // [B,T,HKV,D] fp32

  const size_t M = (size_t)B_ * T_;  // 4096
  char* ws = (char*)d_ws;
  size_t off = 0;
  auto take = [&](size_t elems) { bf16_t* p = (bf16_t*)(ws + off); off += elems * sizeof(bf16_t); return p; };

  bf16_t* Qp = take(M * DIM_);     // Q, later aliased as attention output Y
  bf16_t* Kp = take(M * KVDIM_);
  bf16_t* Vb = take(M * KVDIM_);

  const size_t cvt_elems = M * DIM_ + (size_t)3072 * DIM_ + (size_t)DIM_ * DIM_;
  const bool fast = (ws_size >= off + cvt_elems * sizeof(bf16_t));

  dim3 blk(256);
  if (fast) {
    bf16_t* xb     = take(M * DIM_);
    bf16_t* Wqkvb  = take((size_t)3072 * DIM_);  // Wq | Wk | Wv rows
    bf16_t* Wpb    = take((size_t)DIM_ * DIM_);

    cvt_all<<<dim3(9216), blk, 0, stream>>>(x, Wq, Wk, Wv, Wproj, xb, Wqkvb, Wpb);

    gemm128<1, true, true><<<dim3(3072 / 128, M / 128), blk, 0, stream>>>(
        xb, Wqkvb, nullptr, Qp, Kp, Vb, vout, M, 3072, DIM_);

    qk_norm_rope<<<dim3((unsigned)((M * H_ + M * HKV_) / 4)), blk, 0, stream>>>(Qp, Kp, qgain);
    flash_attn<<<dim3(16, H_, B_), blk, 0, stream>>>(Qp, Kp, Vb, Qp);

    gemm128<2, true, true><<<dim3(DIM_ / 128, M / 128), blk, 0, stream>>>(
        Qp, Wpb, nullptr, out, nullptr, nullptr, nullptr, M, DIM_, DIM_);
  } else {
    gemm128<0, false, false><<<dim3(DIM_ / 128, M / 128), blk, 0, stream>>>(
        x, Wq, nullptr, Qp, nullptr, nullptr, nullptr, M, DIM_, DIM_);
    gemm128<3, false, false><<<dim3(2 * KVDIM_ / 128, M / 128), blk, 0, stream>>>(
        x, Wk, Wv, Kp, nullptr, Vb, vout, M, 2 * KVDIM_, DIM_);
    qk_norm_rope<<<dim3((unsigned)((M * H_ + M * HKV_) / 4)), blk, 0, stream>>>(Qp, Kp, qgain);
    flash_attn<<<dim3(16, H_, B_), blk, 0, stream>>>(Qp, Kp, Vb, Qp);
    gemm128<2, true, false><<<dim3(DIM_ / 128, M / 128), blk, 0, stream>>>(
        Qp, Wproj, nullptr, out, nullptr, nullptr, nullptr, M, DIM_, DIM_);
  }
}